// Round 8
// baseline (178.161 us; speedup 1.0000x reference)
//
#include <hip/hip_runtime.h>

// Depthwise 7x7 true-convolution (flipped kernel, SAME zero pad) + mish.
// x: [16,64,256,256] f32, kernel: [7,7] f32 (shared by all planes).
//
// Round-8 = round-7 with the h2 type fixed (__fp16, matching cvt_pkrtz /
// fdot2 builtin signatures). f16 LDS tile + v_dot2_f32_f16 inner loop
// (fp32 accumulate). Tile 64w x 64h, 256 threads, thread = 8 cols x 2 rows.
// Input tile 70 rows x 72 halfs (9 granules of 8 halfs = 16B), row stride
// 12 granules (192 B, 13.4 KB total). Reads: 2 x ds_read_b128 per row;
// bank group of granule = (tx + k + 4*rr) mod 8 -> all 8 groups uniform
// (8 lanes each) = b128 hardware minimum, no swizzle needed.
// Math: 4 dot2 per (row, output): data pairs are natural dwords (odd col)
// or alignbit-shifted dwords (even col); weight pair is column-independent
// -> 28 uniform packed-f16 weight dwords in SGPRs. Mish in fp32.

#define HW 256
#define TILE_W 64
#define TILE_H 64
#define LR 70            // input rows: 64 + 6 halo
#define NG 9             // data granules per row (72 halfs)
#define NGP 12           // padded granule row stride (192 B)
#define NSLOT (LR * NG)  // 630 staging granules

typedef __fp16 h2 __attribute__((ext_vector_type(2)));
union U32H2 { unsigned i; h2 h; };

__device__ __forceinline__ float fdot2u(unsigned a, unsigned b, float c) {
    U32H2 ua, ub; ua.i = a; ub.i = b;
    return __builtin_amdgcn_fdot2(ua.h, ub.h, c, false);
}

__device__ __forceinline__ float mish_f(float y) {
    float t = __expf(y);            // inf-safe: d -> inf -> 2/d -> 0 -> y*1
    float u = 1.0f + t;
    float d = __fmaf_rn(u, u, 1.0f);
    return y * (1.0f - __fdividef(2.0f, d));
}

__global__ __launch_bounds__(256)
__attribute__((amdgpu_waves_per_eu(4, 8)))
void dwconv7_mish_kernel(const float* __restrict__ x,
                         const float* __restrict__ kern,
                         float* __restrict__ out) {
    __shared__ uint4 smemU4[LR * NGP];   // 13,440 B

    const int tid = threadIdx.x;
    const int tx  = tid & 7;             // 8 strips x 8 cols = 64 wide
    const int ty2 = tid >> 3;            // 32 row-pairs -> 64 rows
    const int col0 = blockIdx.x * TILE_W;
    const int row0 = blockIdx.y * TILE_H;
    const int plane = blockIdx.z;        // b*64 + c

    const float* __restrict__ xp = x + (size_t)plane * (HW * HW);
    float* __restrict__ op = out + (size_t)plane * (HW * HW);

    // Flipped kernel, packed f16 pairs in SGPRs:
    // wA[p][t] = pack(kf[p][2t], kf[p][2t+1]), kf[p][q] = kern[6-p][6-q],
    // kf[p][7] := 0.
    unsigned wA[7][4];
    #pragma unroll
    for (int p = 0; p < 7; ++p) {
        #pragma unroll
        for (int t = 0; t < 4; ++t) {
            float lo = kern[(6 - p) * 7 + (6 - 2 * t)];
            float hi = (t < 3) ? kern[(6 - p) * 7 + (5 - 2 * t)] : 0.0f;
            U32H2 u; u.h = __builtin_amdgcn_cvt_pkrtz(lo, hi);
            wA[p][t] = __builtin_amdgcn_readfirstlane(u.i);
        }
    }

    // Stage input tile as f16. Granule g covers data cols 8g-4 .. 8g+3
    // (global cols col0+8g-4 ..), i.e. two aligned float4 loads -> 4
    // cvt_pkrtz -> one 16B LDS granule.
    #pragma unroll
    for (int it = 0; it < 3; ++it) {
        int s = tid + it * 256;
        if (s < NSLOT) {
            int r  = s / NG;
            int c8 = s - r * NG;
            int gr = row0 - 3 + r;
            int gc = col0 + c8 * 8 - 4;
            float4 f0 = make_float4(0.f, 0.f, 0.f, 0.f);
            float4 f1 = make_float4(0.f, 0.f, 0.f, 0.f);
            if ((unsigned)gr < (unsigned)HW) {
                const float* rowp = xp + (gr << 8);
                if ((unsigned)gc       <= (unsigned)(HW - 4)) f0 = *(const float4*)(rowp + gc);
                if ((unsigned)(gc + 4) <= (unsigned)(HW - 4)) f1 = *(const float4*)(rowp + gc + 4);
            }
            U32H2 w0, w1, w2, w3;
            w0.h = __builtin_amdgcn_cvt_pkrtz(f0.x, f0.y);
            w1.h = __builtin_amdgcn_cvt_pkrtz(f0.z, f0.w);
            w2.h = __builtin_amdgcn_cvt_pkrtz(f1.x, f1.y);
            w3.h = __builtin_amdgcn_cvt_pkrtz(f1.z, f1.w);
            uint4 g; g.x = w0.i; g.y = w1.i; g.z = w2.i; g.w = w3.i;
            smemU4[r * NGP + c8] = g;
        }
    }
    __syncthreads();

    // Thread: out rows 2*ty2+{0,1}, cols 8*tx..8*tx+7.
    // Window h[0..15] = data cols 8tx-4 .. 8tx+11 = granules tx, tx+1.
    float acc0[8], acc1[8];
    #pragma unroll
    for (int c = 0; c < 8; ++c) { acc0[c] = 0.f; acc1[c] = 0.f; }

    #pragma unroll
    for (int rr = 0; rr < 8; ++rr) {
        const int lr = 2 * ty2 + rr;
        const uint4 A = smemU4[lr * NGP + tx];
        const uint4 B = smemU4[lr * NGP + tx + 1];
        unsigned us[8] = {A.x, A.y, A.z, A.w, B.x, B.y, B.z, B.w};
        unsigned vs[7];
        #pragma unroll
        for (int k = 0; k < 7; ++k)
            vs[k] = __builtin_amdgcn_alignbit(us[k + 1], us[k], 16);

        // out row j gets kernel row p = rr - j
        if (rr <= 6) {                       // j = 0, p = rr
            #pragma unroll
            for (int t = 0; t < 4; ++t) {
                const unsigned w = wA[rr][t];
                #pragma unroll
                for (int cc = 0; cc < 4; ++cc) {
                    acc0[2 * cc]     = fdot2u(vs[cc + t],     w, acc0[2 * cc]);
                    acc0[2 * cc + 1] = fdot2u(us[cc + 1 + t], w, acc0[2 * cc + 1]);
                }
            }
        }
        if (rr >= 1) {                       // j = 1, p = rr - 1
            #pragma unroll
            for (int t = 0; t < 4; ++t) {
                const unsigned w = wA[rr - 1][t];
                #pragma unroll
                for (int cc = 0; cc < 4; ++cc) {
                    acc1[2 * cc]     = fdot2u(vs[cc + t],     w, acc1[2 * cc]);
                    acc1[2 * cc + 1] = fdot2u(us[cc + 1 + t], w, acc1[2 * cc + 1]);
                }
            }
        }
    }

    {
        float4 o0, o1;
        o0.x = mish_f(acc0[0]); o0.y = mish_f(acc0[1]);
        o0.z = mish_f(acc0[2]); o0.w = mish_f(acc0[3]);
        o1.x = mish_f(acc0[4]); o1.y = mish_f(acc0[5]);
        o1.z = mish_f(acc0[6]); o1.w = mish_f(acc0[7]);
        float* dst = op + (row0 + 2 * ty2) * HW + col0 + tx * 8;
        *(float4*)(dst)     = o0;
        *(float4*)(dst + 4) = o1;
    }
    {
        float4 o0, o1;
        o0.x = mish_f(acc1[0]); o0.y = mish_f(acc1[1]);
        o0.z = mish_f(acc1[2]); o0.w = mish_f(acc1[3]);
        o1.x = mish_f(acc1[4]); o1.y = mish_f(acc1[5]);
        o1.z = mish_f(acc1[6]); o1.w = mish_f(acc1[7]);
        float* dst = op + (row0 + 2 * ty2 + 1) * HW + col0 + tx * 8;
        *(float4*)(dst)     = o0;
        *(float4*)(dst + 4) = o1;
    }
}

extern "C" void kernel_launch(void* const* d_in, const int* in_sizes, int n_in,
                              void* d_out, int out_size, void* d_ws, size_t ws_size,
                              hipStream_t stream) {
    const float* x = (const float*)d_in[0];
    const float* k = (const float*)d_in[1];
    float* out = (float*)d_out;

    dim3 grid(HW / TILE_W, HW / TILE_H, 16 * 64);  // 4 x 4 x 1024
    dim3 block(256);
    dwconv7_mish_kernel<<<grid, block, 0, stream>>>(x, k, out);
}